// Round 4
// baseline (251.627 us; speedup 1.0000x reference)
//
#include <hip/hip_runtime.h>

// YOLOv1 loss forward, MI355X.
// preds/labels: (16384, 7, 7, 30) fp32, cell = 30 contiguous floats.
// R1 (42.5us): two 30.7KB LDS buffers, BLOCK=256 -> 2 blocks/CU, latency-bound.
// R2 (341us): conditional reg-array staging -> scratch spill (VGPR 44).
// R3 (142us): float p[30] reg array -> scratch again (VGPR 44, L2-resident:
//             WRITE_SIZE ~0 but VALUBusy 3%). Rule: NO per-thread arrays.
// R4: R1's exact compute body (LDS-direct scalars, VGPR 88 proven) +
//     BLOCK=128 (30.7KB total LDS -> 5 blocks/CU = 10 waves/CU) +
//     R3's proven fused last-block finish.

#define NCELLS   802816                // 16384*7*7
#define CH       30
#define BLOCK    128
#define NBLOCKS  (NCELLS / BLOCK)      // 6272, exact
#define NVEC     (BLOCK * CH / 4)      // 960 float4 per array per block
#define BATCH    16384.0

__device__ __forceinline__ float sq(float x) { return x * x; }

__device__ __forceinline__ float iou_f(float bx, float by, float bw, float bh,
                                       float lx, float ly, float lw, float lh) {
    float area1 = bw * bh;
    float area2 = lw * lh;
    float max_left  = fmaxf(bx - bw * 0.5f, lx - lw * 0.5f);
    float min_right = fminf(bx + bw * 0.5f, lx + lw * 0.5f);
    float max_top   = fmaxf(by - bh * 0.5f, ly - lh * 0.5f);
    float min_bot   = fminf(by + bh * 0.5f, ly + lh * 0.5f);
    float iw = min_right - max_left;
    float ih = min_bot - max_top;
    float inter = iw * ih;
    float iou = inter / (area1 + area2 - inter);
    return (iw > 0.f && ih > 0.f) ? iou : 0.f;
}

__global__ __launch_bounds__(BLOCK) void yolo_fused(
        const float* __restrict__ preds,
        const float* __restrict__ labels,
        float* __restrict__ partials,
        unsigned int* __restrict__ counter,
        float* __restrict__ out) {
    __shared__ alignas(16) float sp[BLOCK * CH];   // 15360 B
    __shared__ alignas(16) float sl[BLOCK * CH];   // 15360 B
    __shared__ float warp_s[2];
    __shared__ int s_last;

    const int tid = threadIdx.x;
    const long base4 = (long)blockIdx.x * NVEC;
    const float4* p4 = reinterpret_cast<const float4*>(preds) + base4;
    const float4* l4 = reinterpret_cast<const float4*>(labels) + base4;
    float4* sp4 = reinterpret_cast<float4*>(sp);
    float4* sl4 = reinterpret_cast<float4*>(sl);

    // Stage BOTH arrays concurrently (all loads in flight before the barrier).
    for (int i = tid; i < NVEC; i += BLOCK) {
        sp4[i] = p4[i];
        sl4[i] = l4[i];
    }
    __syncthreads();

    // Compute directly from LDS — named scalars only (R1-proven, no spill).
    const float* P = sp + tid * CH;
    const float* L = sl + tid * CH;

    float p0 = P[0], p1 = P[1], p2 = P[2], p3 = P[3], pc1 = P[4];
    float q0 = P[5], q1 = P[6], q2 = P[7], q3 = P[8], pc2 = P[9];
    float l0 = L[0], l1 = L[1], l2 = L[2], l3 = L[3], lobj = L[4];

    const bool obj = (lobj == 1.0f);

    float cls = 0.f;
    #pragma unroll
    for (int c = 10; c < CH; ++c) {
        float d = L[c] - P[c];
        cls += d * d;
    }

    float iou1 = iou_f(p0, p1, p2, p3, l0, l1, l2, l3);
    float iou2 = iou_f(q0, q1, q2, q3, l0, l1, l2, l3);
    const bool sel1 = iou1 > iou2;

    float xy1 = sq(l0 - p0) + sq(l1 - p1);
    float xy2 = sq(l0 - q0) + sq(l1 - q1);

    float sl2 = sqrtf(l2), sl3 = sqrtf(l3);
    float wh1 = sq(sl2 - sqrtf(p2)) + sq(sl3 - sqrtf(p3));
    float wh2 = sq(sl2 - sqrtf(q2)) + sq(sl3 - sqrtf(q3));

    float o1 = sq(iou1 - pc1);
    float o2 = sq(iou2 - pc2);

    float n1 = pc2 * pc2;   // sel1 responsible -> penalize other box's conf
    float n2 = pc1 * pc1;

    float contrib;
    if (obj) {
        float xyt = sel1 ? xy1 : xy2;
        float wht = sel1 ? wh1 : wh2;
        float ot  = sel1 ? o1  : o2;
        float nt  = sel1 ? n1  : n2;
        contrib = 5.0f * xyt + wht + ot + 0.5f * nt + cls;
    } else {
        contrib = 0.5f * (pc1 * pc1 + pc2 * pc2);
    }

    // wave-64 reduction -> block partial (2 waves)
    float v = contrib;
    #pragma unroll
    for (int off = 32; off > 0; off >>= 1)
        v += __shfl_down(v, off, 64);
    if ((tid & 63) == 0) warp_s[tid >> 6] = v;
    __syncthreads();

    if (tid == 0) {
        float part = warp_s[0] + warp_s[1];
        __hip_atomic_store(&partials[blockIdx.x], part,
                           __ATOMIC_RELAXED, __HIP_MEMORY_SCOPE_AGENT);
        __threadfence();   // device-scope release of the partial
        unsigned int old = __hip_atomic_fetch_add(counter, 1u,
                           __ATOMIC_ACQ_REL, __HIP_MEMORY_SCOPE_AGENT);
        s_last = (old == NBLOCKS - 1);
    }
    __syncthreads();

    if (s_last) {
        __threadfence();   // acquire: all partials visible (device scope)
        double acc = 0.0;
        for (int i = tid; i < NBLOCKS; i += BLOCK)
            acc += (double)__hip_atomic_load(&partials[i],
                           __ATOMIC_RELAXED, __HIP_MEMORY_SCOPE_AGENT);
        double* sd = reinterpret_cast<double*>(sp);   // staging done
        __syncthreads();
        sd[tid] = acc;
        __syncthreads();
        for (int off = BLOCK / 2; off > 0; off >>= 1) {
            if (tid < off) sd[tid] += sd[tid + off];
            __syncthreads();
        }
        if (tid == 0) out[0] = (float)(sd[0] / BATCH);
    }
}

extern "C" void kernel_launch(void* const* d_in, const int* in_sizes, int n_in,
                              void* d_out, int out_size, void* d_ws, size_t ws_size,
                              hipStream_t stream) {
    const float* preds  = (const float*)d_in[0];
    const float* labels = (const float*)d_in[1];
    float* out = (float*)d_out;

    unsigned int* counter = (unsigned int*)d_ws;             // 4 B
    float* partials = (float*)((char*)d_ws + 256);           // 25 KB

    hipMemsetAsync(counter, 0, sizeof(unsigned int), stream);
    yolo_fused<<<NBLOCKS, BLOCK, 0, stream>>>(preds, labels, partials, counter, out);
}

// Round 5
// 37.446 us; speedup vs baseline: 6.7197x; 6.7197x over previous
//
#include <hip/hip_runtime.h>

// YOLOv1 loss forward, MI355X.
// preds/labels: (16384, 7, 7, 30) fp32, cell = 30 contiguous floats.
// R1 (42.5us, best): two 30.7KB LDS buffers, BLOCK=256, two-kernel reduce.
// R2 (341us): conditional reg-array staging -> scratch spill.
// R3 (142us): float p[30] reg array -> scratch; fence structure also slow.
// R4 (251us): fused last-block finish refuted: per-block __threadfence +
//             acq-rel atomic ~ L2 writeback, serial, ~37us/1000 blocks.
//             L3-resident replays equally slow -> overhead, not BW.
// R5: R1 + __builtin_amdgcn_global_load_lds width=16 staging (no VGPR
//     round-trip, 15 loads/thread all in flight). No fences, no atomics.

#define NCELLS   802816                // 16384*7*7
#define CH       30
#define BLOCK    256
#define NBLOCKS  (NCELLS / BLOCK)      // 3136, exact
#define NVEC     (BLOCK * CH / 4)      // 1920 float4 per array per block
#define BATCH    16384.0

#define GLOAD16(gaddr, laddr)                                                  \
    __builtin_amdgcn_global_load_lds(                                          \
        (const __attribute__((address_space(1))) unsigned int*)(gaddr),        \
        (__attribute__((address_space(3))) unsigned int*)(laddr), 16, 0, 0)

__device__ __forceinline__ float sq(float x) { return x * x; }

__device__ __forceinline__ float iou_f(float bx, float by, float bw, float bh,
                                       float lx, float ly, float lw, float lh) {
    float area1 = bw * bh;
    float area2 = lw * lh;
    float max_left  = fmaxf(bx - bw * 0.5f, lx - lw * 0.5f);
    float min_right = fminf(bx + bw * 0.5f, lx + lw * 0.5f);
    float max_top   = fmaxf(by - bh * 0.5f, ly - lh * 0.5f);
    float min_bot   = fminf(by + bh * 0.5f, ly + lh * 0.5f);
    float iw = min_right - max_left;
    float ih = min_bot - max_top;
    float inter = iw * ih;
    float iou = inter / (area1 + area2 - inter);
    return (iw > 0.f && ih > 0.f) ? iou : 0.f;
}

__global__ __launch_bounds__(BLOCK) void yolo_loss_main(
        const float* __restrict__ preds,
        const float* __restrict__ labels,
        float* __restrict__ partials) {
    __shared__ alignas(16) float sp[BLOCK * CH];   // 30720 B
    __shared__ alignas(16) float sl[BLOCK * CH];   // 30720 B
    __shared__ float warp_s[4];

    const int tid = threadIdx.x;
    const long base4 = (long)blockIdx.x * NVEC;
    const float4* p4 = reinterpret_cast<const float4*>(preds) + base4;
    const float4* l4 = reinterpret_cast<const float4*>(labels) + base4;
    float4* sp4 = reinterpret_cast<float4*>(sp);
    float4* sl4 = reinterpret_cast<float4*>(sl);

    // Async global->LDS staging, width 16. LDS dest is linear in lane order
    // (lane l -> wave_base + l*16). Last iteration's guard (idx<1920 ->
    // tid<128) splits exactly at a 2-wave boundary: wave-uniform branch.
    #pragma unroll
    for (int i = 0; i < 8; ++i) {
        int idx = i * BLOCK + tid;
        if (idx < NVEC) {
            GLOAD16(p4 + idx, sp4 + idx);
            GLOAD16(l4 + idx, sl4 + idx);
        }
    }
    __syncthreads();   // compiler emits s_waitcnt vmcnt(0) before s_barrier

    // Compute directly from LDS — named scalars only (no per-thread arrays).
    const float* P = sp + tid * CH;
    const float* L = sl + tid * CH;

    float p0 = P[0], p1 = P[1], p2 = P[2], p3 = P[3], pc1 = P[4];
    float q0 = P[5], q1 = P[6], q2 = P[7], q3 = P[8], pc2 = P[9];
    float l0 = L[0], l1 = L[1], l2 = L[2], l3 = L[3], lobj = L[4];

    const bool obj = (lobj == 1.0f);

    float cls = 0.f;
    #pragma unroll
    for (int c = 10; c < CH; ++c) {
        float d = L[c] - P[c];
        cls += d * d;
    }

    float iou1 = iou_f(p0, p1, p2, p3, l0, l1, l2, l3);
    float iou2 = iou_f(q0, q1, q2, q3, l0, l1, l2, l3);
    const bool sel1 = iou1 > iou2;

    float xy1 = sq(l0 - p0) + sq(l1 - p1);
    float xy2 = sq(l0 - q0) + sq(l1 - q1);

    float sl2 = sqrtf(l2), sl3 = sqrtf(l3);
    float wh1 = sq(sl2 - sqrtf(p2)) + sq(sl3 - sqrtf(p3));
    float wh2 = sq(sl2 - sqrtf(q2)) + sq(sl3 - sqrtf(q3));

    float o1 = sq(iou1 - pc1);
    float o2 = sq(iou2 - pc2);

    float n1 = pc2 * pc2;   // sel1 responsible -> penalize other box's conf
    float n2 = pc1 * pc1;

    float contrib;
    if (obj) {
        float xyt = sel1 ? xy1 : xy2;
        float wht = sel1 ? wh1 : wh2;
        float ot  = sel1 ? o1  : o2;
        float nt  = sel1 ? n1  : n2;
        contrib = 5.0f * xyt + wht + ot + 0.5f * nt + cls;
    } else {
        contrib = 0.5f * (pc1 * pc1 + pc2 * pc2);
    }

    // wave-64 reduction -> block partial
    float v = contrib;
    #pragma unroll
    for (int off = 32; off > 0; off >>= 1)
        v += __shfl_down(v, off, 64);
    if ((tid & 63) == 0) warp_s[tid >> 6] = v;
    __syncthreads();
    if (tid == 0)
        partials[blockIdx.x] = warp_s[0] + warp_s[1] + warp_s[2] + warp_s[3];
}

__global__ __launch_bounds__(BLOCK) void yolo_loss_final(
        const float* __restrict__ partials,
        float* __restrict__ out) {
    __shared__ double s[BLOCK];
    double acc = 0.0;
    for (int i = threadIdx.x; i < NBLOCKS; i += BLOCK)
        acc += (double)partials[i];
    s[threadIdx.x] = acc;
    __syncthreads();
    for (int off = BLOCK / 2; off > 0; off >>= 1) {
        if (threadIdx.x < off) s[threadIdx.x] += s[threadIdx.x + off];
        __syncthreads();
    }
    if (threadIdx.x == 0) out[0] = (float)(s[0] / BATCH);
}

extern "C" void kernel_launch(void* const* d_in, const int* in_sizes, int n_in,
                              void* d_out, int out_size, void* d_ws, size_t ws_size,
                              hipStream_t stream) {
    const float* preds  = (const float*)d_in[0];
    const float* labels = (const float*)d_in[1];
    float* out      = (float*)d_out;
    float* partials = (float*)d_ws;   // 3136 floats = 12.5 KB

    yolo_loss_main<<<NBLOCKS, BLOCK, 0, stream>>>(preds, labels, partials);
    yolo_loss_final<<<1, BLOCK, 0, stream>>>(partials, out);
}